// Round 2
// baseline (247.480 us; speedup 1.0000x reference)
//
#include <hip/hip_runtime.h>

#define B_ 2
#define H_ 16
#define S_ 2048
#define DM 1024
#define DK 64
#define NX (4096 * 1024)   // q/k/v element count
#define NW (1024 * 1024)   // W element count

typedef unsigned short u16;
typedef __attribute__((ext_vector_type(8))) short bf16x8;          // MFMA A/B frag
typedef __attribute__((ext_vector_type(8))) unsigned short u16x8;  // 16-byte unit
typedef __attribute__((ext_vector_type(4))) unsigned short u16x4;  // 8-byte unit
typedef __attribute__((ext_vector_type(2))) unsigned int u32x2;    // 8-byte unit
typedef __attribute__((ext_vector_type(4))) float f32x4;           // MFMA C/D

__device__ inline u16 f2bf(float f) {                       // RNE float->bf16
  union { float f; unsigned int u; } c; c.f = f;
  unsigned int u = c.u;
  u += 0x7fffu + ((u >> 16) & 1u);
  return (u16)(u >> 16);
}

__device__ inline u16x8 cvt8(const float* __restrict__ src) {
  const float4 a = *reinterpret_cast<const float4*>(src);
  const float4 b = *reinterpret_cast<const float4*>(src + 4);
  u16x8 r;
  r[0] = f2bf(a.x); r[1] = f2bf(a.y); r[2] = f2bf(a.z); r[3] = f2bf(a.w);
  r[4] = f2bf(b.x); r[5] = f2bf(b.y); r[6] = f2bf(b.z); r[7] = f2bf(b.w);
  return r;
}

__device__ inline void glds16(const u16* g, u16* l) {       // async global->LDS, 16B/lane
  __builtin_amdgcn_global_load_lds(
      (const __attribute__((address_space(1))) unsigned int*)g,
      (__attribute__((address_space(3))) unsigned int*)l, 16, 0, 0);
}

__device__ inline unsigned cvtpk(float lo, float hi) {      // pack 2xf32 -> 2xbf16 (RNE)
  unsigned r;
  asm("v_cvt_pk_bf16_f32 %0, %1, %2" : "=v"(r) : "v"(lo), "v"(hi));
  return r;
}

// ---------------------------------------------------------------------------
// Prepass: fp32 -> bf16 once per tensor.
// ---------------------------------------------------------------------------
__global__ __launch_bounds__(256) void cvt_kernel(
    const float* __restrict__ q, const float* __restrict__ k, const float* __restrict__ v,
    const float* __restrict__ Wq, const float* __restrict__ Wk, const float* __restrict__ Wv,
    u16* __restrict__ Xq, u16* __restrict__ Xk, u16* __restrict__ Xv,
    u16* __restrict__ Wqb, u16* __restrict__ Wkb, u16* __restrict__ Wvb)
{
  const int t = blockIdx.y;
  const float* src = (t == 0) ? q : (t == 1) ? k : (t == 2) ? v
                   : (t == 3) ? Wq : (t == 4) ? Wk : Wv;
  u16* dst = (t == 0) ? Xq : (t == 1) ? Xk : (t == 2) ? Xv
           : (t == 3) ? Wqb : (t == 4) ? Wkb : Wvb;
  const int n = (t < 3) ? NX : NW;
  const int idx = (blockIdx.x * 256 + threadIdx.x) * 8;
  if (idx >= n) return;
  *reinterpret_cast<u16x8*>(&dst[idx]) = cvt8(&src[idx]);
}

// ---------------------------------------------------------------------------
// Projection: Y = X @ W^T + b (bf16, m97-style).
// z=0 (Q): out [bh][s][d], pre-scaled by (1/sqrt(Dk))*log2(e) for exp2 softmax.
// z=1 (K): out [bh][s][d].
// z=2 (V): out written DIRECTLY as Vt [bh][d][s] (transpose fused into the
//          epilogue: r-index is s-consecutive -> vectorized u16x4 stores).
// ---------------------------------------------------------------------------
__global__ __launch_bounds__(256) void proj_kernel(
    const u16* __restrict__ Xq, const u16* __restrict__ Xk, const u16* __restrict__ Xv,
    const u16* __restrict__ Wqb, const u16* __restrict__ Wkb, const u16* __restrict__ Wvb,
    const float* __restrict__ bq, const float* __restrict__ bk, const float* __restrict__ bv,
    u16* __restrict__ Qh, u16* __restrict__ Kh, u16* __restrict__ Vt)
{
  const int z = blockIdx.z;
  const u16* X      = (z == 0) ? Xq : (z == 1) ? Xk : Xv;
  const u16* W      = (z == 0) ? Wqb : (z == 1) ? Wkb : Wvb;
  const float* bias = (z == 0) ? bq : (z == 1) ? bk : bv;
  u16* out          = (z == 0) ? Qh : (z == 1) ? Kh : Vt;
  const float scale = (z == 0) ? 0.18033688f : 1.0f;   // 0.125 * log2(e)

  __shared__ __align__(16) u16 Xs[128 * 32];   // unpadded: required by global_load_lds
  __shared__ __align__(16) u16 Ws[128 * 32];

  const int tid = threadIdx.x;
  const int lane = tid & 63;
  const int w = tid >> 6;
  const int wy = w >> 1, wx = w & 1;
  const int m0 = blockIdx.y * 128;
  const int n0 = blockIdx.x * 128;
  const int ml = lane & 15;
  const int qd = lane >> 4;

  f32x4 acc[4][4] = {};

  for (int kb = 0; kb < DM; kb += 32) {
    __syncthreads();
    #pragma unroll
    for (int p = 0; p < 2; ++p) {
      const int c = p * 4 + w;                  // chunk: 16 rows x 32 cols = 1 KiB
      const int row = c * 16 + (lane >> 2);
      const int col = kb + (lane & 3) * 8;
      glds16(&X[(size_t)(m0 + row) * DM + col], &Xs[c * 512]);
      glds16(&W[(size_t)(n0 + row) * DM + col], &Ws[c * 512]);
    }
    __syncthreads();
    bf16x8 a[4], bfr[4];
    #pragma unroll
    for (int i = 0; i < 4; ++i)
      a[i] = *reinterpret_cast<const bf16x8*>(&Xs[(wy * 64 + i * 16 + ml) * 32 + qd * 8]);
    #pragma unroll
    for (int j = 0; j < 4; ++j)
      bfr[j] = *reinterpret_cast<const bf16x8*>(&Ws[(wx * 64 + j * 16 + ml) * 32 + qd * 8]);
    #pragma unroll
    for (int i = 0; i < 4; ++i)
      #pragma unroll
      for (int j = 0; j < 4; ++j)
        acc[i][j] = __builtin_amdgcn_mfma_f32_16x16x32_bf16(a[i], bfr[j], acc[i][j], 0, 0, 0);
  }

  if (z == 2) {
    // V epilogue: write Vt[bh][d][s]; 4 consecutive r -> 4 consecutive s.
    #pragma unroll
    for (int j = 0; j < 4; ++j) {
      const int n = n0 + wx * 64 + j * 16 + ml;
      const float badd = bias[n];
      const int h = n >> 6, d = n & 63;
      #pragma unroll
      for (int i = 0; i < 4; ++i) {
        const int mb = m0 + wy * 64 + i * 16 + qd * 4;
        const int bi = mb >> 11, s0 = mb & 2047;
        u16x4 pk;
        #pragma unroll
        for (int r = 0; r < 4; ++r) pk[r] = f2bf(acc[i][j][r] + badd);
        *reinterpret_cast<u16x4*>(&out[((size_t)(bi * H_ + h) * DK + d) * S_ + s0]) = pk;
      }
    }
  } else {
    #pragma unroll
    for (int j = 0; j < 4; ++j) {
      const int n = n0 + wx * 64 + j * 16 + ml;
      const float badd = bias[n];
      const int h = n >> 6, d = n & 63;
      #pragma unroll
      for (int i = 0; i < 4; ++i) {
        #pragma unroll
        for (int r = 0; r < 4; ++r) {
          const int m = m0 + wy * 64 + i * 16 + qd * 4 + r;
          const int bi = m >> 11, s = m & 2047;
          out[((bi * H_ + h) * S_ + s) * DK + d] = f2bf((acc[i][j][r] + badd) * scale);
        }
      }
    }
  }
}

// ---------------------------------------------------------------------------
// Flash causal attention, S^T formulation, QBLK=128, KVBLK=64.
// 4 waves; wave w owns 32 q-rows (two 16-row groups g=0,1).
//   - K double-buffered in LDS via global_load_lds (counted vmcnt, 2 barriers).
//   - V fragments loaded GLOBAL->REGISTER directly from Vt[bh][d][s] (tile is
//     L2/L1-resident; offloads the LDS pipe, which was the measured ceiling).
//     Loads issued at loop top (T14 issue-early), consumed after QK+softmax.
//   - vmcnt bookkeeping: per wave per iter exactly 8 V-loads + 2 K-glds are
//     issued between fence-asms -> vmcnt(10) == current K-tile landed (counted,
//     never 0 in-loop). V loads are UNCONDITIONAL so the count is wave-uniform.
//   - K-frag LDS reads hoisted ahead of the MFMA chain; s_setprio around MFMAs.
// ---------------------------------------------------------------------------
__global__ __launch_bounds__(256) void attn_kernel(
    const u16* __restrict__ Qh, const u16* __restrict__ Kh,
    const u16* __restrict__ Vt, float* __restrict__ out)
{
  __shared__ __align__(16) u16 Ks[2][64 * 64];   // [buf][key][dim]   (swizzled)
  __shared__ __align__(16) u16 Ps[4][2][16 * 64];// [wave][g][qrow][key] (swizzled)

  const int tid  = threadIdx.x;
  const int lane = tid & 63;
  const int w    = tid >> 6;

  // XCD-grouped decode: 4 heads per XCD (4 x 512KB K/V = 2MB < 4MB L2),
  // qt longest-first within dispatch order.
  const int fid = blockIdx.x;
  const int bh  = (fid & 7) * 4 + ((fid >> 3) & 3);
  const int qt  = 15 - (fid >> 5);
  const int b   = bh >> 4, h = bh & 15;
  const int ml  = lane & 15, qd = lane >> 4;
  const int m7  = ml & 7;
  const int u0  = qd ^ m7;               // swizzled 16B-col base for K frag reads
  const int qh  = qd >> 1, ql = qd & 1;
  const int R0  = qt * 128;
  const int nt  = 2 * qt + 2;            // # of 64-key tiles

  // Q as B-operand: B[k=dim][n=qrow=ml]; 2 groups x 2 dim-chunks
  bf16x8 qa[2][2];
  #pragma unroll
  for (int g = 0; g < 2; ++g)
    #pragma unroll
    for (int ch = 0; ch < 2; ++ch)
      qa[g][ch] = *reinterpret_cast<const bf16x8*>(
          &Qh[((size_t)bh * S_ + R0 + w * 32 + g * 16 + ml) * DK + ch * 32 + qd * 8]);
  // drain Q loads so manual vmcnt bookkeeping below counts only loop VMEM ops
  asm volatile("s_waitcnt vmcnt(0)" ::: "memory");

  // K staging: 512 16B-chunks per 8KB tile; thread stages chunks tid, tid+256.
  // chunk c -> LDS (row=c>>3, col'=c&7); global source col = (c&7) ^ (row&7)
  const u16* kb0 = Kh + (size_t)bh * S_ * DK;
  const u16* vbase = Vt + (size_t)bh * DK * S_;
  const int r0 = tid >> 3, r1 = r0 + 32;
  const int cs = (tid & 7) ^ (r0 & 7);           // (r1&7)==(r0&7)
  const u16* sK0 = kb0 + r0 * DK + cs * 8;       // advance +4096/tile (64 rows)
  const u16* sK1 = kb0 + r1 * DK + cs * 8;

  f32x4 oacc[2][4] = {};
  float lsum[2] = {0.f, 0.f};

  // prologue: stage K-tile 0 into buf 0 (2 glds16 per wave)
  glds16(sK0, &Ks[0][tid * 8]);
  glds16(sK1, &Ks[0][2048 + tid * 8]);
  sK0 += 4096; sK1 += 4096;

  // per-lane V base: row = dj*16+ml (dim), col = t*64 + c*32 + qd*8 (key)
  const u16* vrow = vbase + (size_t)ml * S_ + qd * 8;

  int cur = 0;
  for (int t = 0; t < nt; ++t) {
    // V-frags for THIS tile, global->reg (issue-early; consumed after QK+SM)
    bf16x8 vf[2][4];
    #pragma unroll
    for (int c = 0; c < 2; ++c)
      #pragma unroll
      for (int dj = 0; dj < 4; ++dj)
        vf[c][dj] = *reinterpret_cast<const bf16x8*>(
            vrow + (size_t)(dj * 16) * S_ + t * 64 + c * 32);

    if (t + 1 < nt) {                            // prefetch next K-tile
      glds16(sK0, &Ks[cur ^ 1][tid * 8]);
      glds16(sK1, &Ks[cur ^ 1][2048 + tid * 8]);
      sK0 += 4096; sK1 += 4096;
      // outstanding: K(t)=2 oldest, V(t)=8, K(t+1)=2 newest -> wait K(t) only
      asm volatile("s_waitcnt vmcnt(10)" ::: "memory");
    } else {
      // outstanding: K(t)=2 oldest, V(t)=8 newest
      asm volatile("s_waitcnt vmcnt(8)" ::: "memory");
    }
    __builtin_amdgcn_s_barrier();
    asm volatile("" ::: "memory");

    const u16* Kb = Ks[cur];

    // wave-uniform causal geometry (see R1): d16g = (rowbase - t*64)/16
    const int d16_0 = (R0 + w * 32 - t * 64) >> 4;
    const int d16_1 = d16_0 + 1;
    const int jtop  = (d16_1 < 3) ? d16_1 : 3;

    if (jtop >= 0) {
      // hoist all needed K-frag reads (break ds_read->MFMA serialization)
      bf16x8 kf[4][2];
      #pragma unroll
      for (int j = 0; j < 4; ++j) {
        if (j > jtop) break;
        const int rk = (j * 16 + ml) * 64;
        kf[j][0] = *reinterpret_cast<const bf16x8*>(&Kb[rk + u0 * 8]);
        kf[j][1] = *reinterpret_cast<const bf16x8*>(&Kb[rk + (u0 ^ 4) * 8]);
      }

      f32x4 sfr[2][4];
      __builtin_amdgcn_s_setprio(1);
      #pragma unroll
      for (int j = 0; j < 4; ++j) {
        if (j > jtop) break;
        #pragma unroll
        for (int g = 0; g < 2; ++g) {
          const int d16g = d16_0 + g;
          if (j > d16g) continue;                // wave-uniform
          f32x4 zz = {};
          zz = __builtin_amdgcn_mfma_f32_16x16x32_bf16(kf[j][0], qa[g][0], zz, 0, 0, 0);
          zz = __builtin_amdgcn_mfma_f32_16x16x32_bf16(kf[j][1], qa[g][1], zz, 0, 0, 0);
          sfr[g][j] = zz;
        }
      }
      __builtin_amdgcn_s_setprio(0);

      // mask + exp2 + row-sum + pack P (cvt_pk) into per-wave Ps
      #pragma unroll
      for (int j = 0; j < 4; ++j) {
        if (j > jtop) break;
        #pragma unroll
        for (int g = 0; g < 2; ++g) {
          const int d16g = d16_0 + g;
          if (j > d16g) continue;
          f32x4 zz = sfr[g][j];
          if (j == d16g) {                       // diagonal subtile mask
            #pragma unroll
            for (int r = 0; r < 4; ++r)
              if (qd * 4 + r > ml) zz[r] = -1e30f;
          }
          const float e0 = __builtin_amdgcn_exp2f(zz[0]);
          const float e1 = __builtin_amdgcn_exp2f(zz[1]);
          const float e2 = __builtin_amdgcn_exp2f(zz[2]);
          const float e3 = __builtin_amdgcn_exp2f(zz[3]);
          lsum[g] += (e0 + e1) + (e2 + e3);
          u32x2 pk;
          pk[0] = cvtpk(e0, e1);
          pk[1] = cvtpk(e2, e3);
          *reinterpret_cast<u32x2*>(
              &Ps[w][g][ml * 64 + (((2 * j + qh) ^ m7) * 8) + ql * 4]) = pk;
        }
      }
      // zero-fill P subtiles covered by an active PV chunk but fully masked
      #pragma unroll
      for (int g = 0; g < 2; ++g) {
        const int d16g = d16_0 + g;
        if (d16g == 0 || d16g == 2) {
          const int jz = d16g + 1;
          *reinterpret_cast<u32x2*>(
              &Ps[w][g][ml * 64 + (((2 * jz + qh) ^ m7) * 8) + ql * 4]) = (u32x2){0, 0};
        }
      }

      // O += P V : A=P (per-wave Ps), B=V^T fragments already in registers
      #pragma unroll
      for (int c = 0; c < 2; ++c) {
        const bool use0 = d16_0 >= 2 * c;
        const bool use1 = d16_1 >= 2 * c;
        if (!(use0 | use1)) continue;            // wave-uniform
        __builtin_amdgcn_s_setprio(1);
        if (use0) {
          const bf16x8 pa = *reinterpret_cast<const bf16x8*>(
              &Ps[w][0][ml * 64 + (u0 ^ (c << 2)) * 8]);
          #pragma unroll
          for (int dj = 0; dj < 4; ++dj)
            oacc[0][dj] = __builtin_amdgcn_mfma_f32_16x16x32_bf16(pa, vf[c][dj], oacc[0][dj], 0, 0, 0);
        }
        if (use1) {
          const bf16x8 pa = *reinterpret_cast<const bf16x8*>(
              &Ps[w][1][ml * 64 + (u0 ^ (c << 2)) * 8]);
          #pragma unroll
          for (int dj = 0; dj < 4; ++dj)
            oacc[1][dj] = __builtin_amdgcn_mfma_f32_16x16x32_bf16(pa, vf[c][dj], oacc[1][dj], 0, 0, 0);
        }
        __builtin_amdgcn_s_setprio(0);
      }
    }

    asm volatile("" ::: "memory");
    __builtin_amdgcn_s_barrier();                // Ks[cur] free for re-stage
    asm volatile("" ::: "memory");
    cur ^= 1;
  }

  // epilogue: complete row-sums across quads, normalize, store fp32
  #pragma unroll
  for (int g = 0; g < 2; ++g) {
    float lg = lsum[g];
    lg += __shfl_xor(lg, 16, 64);
    lg += __shfl_xor(lg, 32, 64);
    #pragma unroll
    for (int r = 0; r < 4; ++r) {
      const float inv = 1.0f / __shfl(lg, qd * 4 + r, 64);
      const int srow = R0 + w * 32 + g * 16 + qd * 4 + r;
      float* op = &out[(size_t)(b * S_ + srow) * DM + h * DK + ml];
      #pragma unroll
      for (int dj = 0; dj < 4; ++dj)
        op[dj * 16] = oacc[g][dj][r] * inv;
    }
  }
}

extern "C" void kernel_launch(void* const* d_in, const int* in_sizes, int n_in,
                              void* d_out, int out_size, void* d_ws, size_t ws_size,
                              hipStream_t stream) {
  // inputs: q,k,v,mask,Wq,bq,Wk,bk,Wv,bv — fp32 (mask int32, unused)
  const float* q  = (const float*)d_in[0];
  const float* k  = (const float*)d_in[1];
  const float* v  = (const float*)d_in[2];
  const float* Wq = (const float*)d_in[4];
  const float* bq = (const float*)d_in[5];
  const float* Wk = (const float*)d_in[6];
  const float* bk = (const float*)d_in[7];
  const float* Wv = (const float*)d_in[8];
  const float* bv = (const float*)d_in[9];

  u16* Xq  = (u16*)d_ws;          // 8 MB each for X*, 2 MB each for W*
  u16* Xk  = Xq + NX;
  u16* Xv  = Xk + NX;
  u16* Wqb = Xv + NX;
  u16* Wkb = Wqb + NW;
  u16* Wvb = Wkb + NW;
  u16* Qh  = Wvb + NW;            // [bh][s][d]
  u16* Kh  = Qh + NX;             // [bh][s][d]
  u16* Vt  = Kh + NX;             // [bh][d][s] — written directly by proj z=2

  cvt_kernel<<<dim3(NX / (256 * 8), 6), 256, 0, stream>>>(
      q, k, v, Wq, Wk, Wv, Xq, Xk, Xv, Wqb, Wkb, Wvb);
  proj_kernel<<<dim3(DM / 128, (B_ * S_) / 128, 3), 256, 0, stream>>>(
      Xq, Xk, Xv, Wqb, Wkb, Wvb, bq, bk, bv, Qh, Kh, Vt);
  attn_kernel<<<dim3(512), 256, 0, stream>>>(
      Qh, Kh, Vt, (float*)d_out);
}

// Round 3
// 219.324 us; speedup vs baseline: 1.1284x; 1.1284x over previous
//
#include <hip/hip_runtime.h>

#define B_ 2
#define H_ 16
#define S_ 2048
#define DM 1024
#define DK 64
#define NX (4096 * 1024)   // q/k/v element count
#define NW (1024 * 1024)   // W element count

typedef unsigned short u16;
typedef __attribute__((ext_vector_type(8))) short bf16x8;          // MFMA A/B frag
typedef __attribute__((ext_vector_type(8))) unsigned short u16x8;  // 16-byte unit
typedef __attribute__((ext_vector_type(4))) unsigned short u16x4;  // 8-byte unit
typedef __attribute__((ext_vector_type(2))) unsigned int u32x2;
typedef __attribute__((ext_vector_type(4))) unsigned int u32x4;
typedef __attribute__((ext_vector_type(4))) float f32x4;           // 16x16 C/D
typedef __attribute__((ext_vector_type(16))) float f32x16;         // 32x32 C/D

__device__ inline u16 f2bf(float f) {                       // RNE float->bf16
  union { float f; unsigned int u; } c; c.f = f;
  unsigned int u = c.u;
  u += 0x7fffu + ((u >> 16) & 1u);
  return (u16)(u >> 16);
}

__device__ inline u16x8 cvt8(const float* __restrict__ src) {
  const float4 a = *reinterpret_cast<const float4*>(src);
  const float4 b = *reinterpret_cast<const float4*>(src + 4);
  u16x8 r;
  r[0] = f2bf(a.x); r[1] = f2bf(a.y); r[2] = f2bf(a.z); r[3] = f2bf(a.w);
  r[4] = f2bf(b.x); r[5] = f2bf(b.y); r[6] = f2bf(b.z); r[7] = f2bf(b.w);
  return r;
}

__device__ inline void glds16(const u16* g, u16* l) {       // async global->LDS, 16B/lane
  __builtin_amdgcn_global_load_lds(
      (const __attribute__((address_space(1))) unsigned int*)g,
      (__attribute__((address_space(3))) unsigned int*)l, 16, 0, 0);
}

__device__ inline unsigned cvtpk(float lo, float hi) {      // pack 2xf32 -> 2xbf16 (RNE)
  unsigned r;
  asm("v_cvt_pk_bf16_f32 %0, %1, %2" : "=v"(r) : "v"(lo), "v"(hi));
  return r;
}

// permlane32_swap: a.hi-lanes <-> b.lo-lanes (lane l pairs with l^32).
// After: a = {lo: a_old(own), hi: b_old(partner-lo)}, b = {lo: a_old(partner-hi), hi: b_old(own)}.
#if __has_builtin(__builtin_amdgcn_permlane32_swap)
__device__ inline void plswap(unsigned& a, unsigned& b) {
  auto r = __builtin_amdgcn_permlane32_swap(a, b, false, false);
  a = r[0]; b = r[1];
}
#else
__device__ inline void plswap(unsigned& a, unsigned& b) {
  const unsigned pa = (unsigned)__shfl_xor((int)a, 32, 64);
  const unsigned pb = (unsigned)__shfl_xor((int)b, 32, 64);
  const bool hi = (threadIdx.x & 32) != 0;
  const unsigned na = hi ? pb : a;
  const unsigned nb = hi ? b : pa;
  a = na; b = nb;
}
#endif

// ---------------------------------------------------------------------------
// Prepass: fp32 -> bf16 once per tensor.
// ---------------------------------------------------------------------------
__global__ __launch_bounds__(256) void cvt_kernel(
    const float* __restrict__ q, const float* __restrict__ k, const float* __restrict__ v,
    const float* __restrict__ Wq, const float* __restrict__ Wk, const float* __restrict__ Wv,
    u16* __restrict__ Xq, u16* __restrict__ Xk, u16* __restrict__ Xv,
    u16* __restrict__ Wqb, u16* __restrict__ Wkb, u16* __restrict__ Wvb)
{
  const int t = blockIdx.y;
  const float* src = (t == 0) ? q : (t == 1) ? k : (t == 2) ? v
                   : (t == 3) ? Wq : (t == 4) ? Wk : Wv;
  u16* dst = (t == 0) ? Xq : (t == 1) ? Xk : (t == 2) ? Xv
           : (t == 3) ? Wqb : (t == 4) ? Wkb : Wvb;
  const int n = (t < 3) ? NX : NW;
  const int idx = (blockIdx.x * 256 + threadIdx.x) * 8;
  if (idx >= n) return;
  *reinterpret_cast<u16x8*>(&dst[idx]) = cvt8(&src[idx]);
}

// ---------------------------------------------------------------------------
// Projection: Y = X @ W^T + b (bf16, m97-style). ALL outputs [bh][s][d]
// (coalesced stores). z=0 (Q) pre-scaled by (1/sqrt(Dk))*log2(e) for exp2.
// ---------------------------------------------------------------------------
__global__ __launch_bounds__(256) void proj_kernel(
    const u16* __restrict__ Xq, const u16* __restrict__ Xk, const u16* __restrict__ Xv,
    const u16* __restrict__ Wqb, const u16* __restrict__ Wkb, const u16* __restrict__ Wvb,
    const float* __restrict__ bq, const float* __restrict__ bk, const float* __restrict__ bv,
    u16* __restrict__ Qh, u16* __restrict__ Kh, u16* __restrict__ Vh)
{
  const int z = blockIdx.z;
  const u16* X      = (z == 0) ? Xq : (z == 1) ? Xk : Xv;
  const u16* W      = (z == 0) ? Wqb : (z == 1) ? Wkb : Wvb;
  const float* bias = (z == 0) ? bq : (z == 1) ? bk : bv;
  u16* out          = (z == 0) ? Qh : (z == 1) ? Kh : Vh;
  const float scale = (z == 0) ? 0.18033688f : 1.0f;   // 0.125 * log2(e)

  __shared__ __align__(16) u16 Xs[128 * 32];   // unpadded: required by global_load_lds
  __shared__ __align__(16) u16 Ws[128 * 32];

  const int tid = threadIdx.x;
  const int lane = tid & 63;
  const int w = tid >> 6;
  const int wy = w >> 1, wx = w & 1;
  const int m0 = blockIdx.y * 128;
  const int n0 = blockIdx.x * 128;
  const int ml = lane & 15;
  const int qd = lane >> 4;

  f32x4 acc[4][4] = {};

  for (int kb = 0; kb < DM; kb += 32) {
    __syncthreads();
    #pragma unroll
    for (int p = 0; p < 2; ++p) {
      const int c = p * 4 + w;                  // chunk: 16 rows x 32 cols = 1 KiB
      const int row = c * 16 + (lane >> 2);
      const int col = kb + (lane & 3) * 8;
      glds16(&X[(size_t)(m0 + row) * DM + col], &Xs[c * 512]);
      glds16(&W[(size_t)(n0 + row) * DM + col], &Ws[c * 512]);
    }
    __syncthreads();
    bf16x8 a[4], bfr[4];
    #pragma unroll
    for (int i = 0; i < 4; ++i)
      a[i] = *reinterpret_cast<const bf16x8*>(&Xs[(wy * 64 + i * 16 + ml) * 32 + qd * 8]);
    #pragma unroll
    for (int j = 0; j < 4; ++j)
      bfr[j] = *reinterpret_cast<const bf16x8*>(&Ws[(wx * 64 + j * 16 + ml) * 32 + qd * 8]);
    #pragma unroll
    for (int i = 0; i < 4; ++i)
      #pragma unroll
      for (int j = 0; j < 4; ++j)
        acc[i][j] = __builtin_amdgcn_mfma_f32_16x16x32_bf16(a[i], bfr[j], acc[i][j], 0, 0, 0);
  }

  #pragma unroll
  for (int j = 0; j < 4; ++j) {
    const int n = n0 + wx * 64 + j * 16 + ml;
    const float badd = bias[n];
    const int h = n >> 6, d = n & 63;
    #pragma unroll
    for (int i = 0; i < 4; ++i) {
      #pragma unroll
      for (int r = 0; r < 4; ++r) {
        const int m = m0 + wy * 64 + i * 16 + qd * 4 + r;
        const int bi = m >> 11, s = m & 2047;
        out[((bi * H_ + h) * S_ + s) * DK + d] = f2bf((acc[i][j][r] + badd) * scale);
      }
    }
  }
}

// ---------------------------------------------------------------------------
// Vh[bh][s][d] -> Vt[bh][d][s]  (64x64 LDS tile transpose, coalesced both ways)
// ---------------------------------------------------------------------------
__global__ __launch_bounds__(256) void transpose_kernel(
    const u16* __restrict__ Vh, u16* __restrict__ Vt)
{
  __shared__ __align__(16) u16 T[64 * 72];
  const int t = threadIdx.x;
  const int st = blockIdx.x, bh = blockIdx.y;
  {
    const int r = t >> 2, c = (t & 3) * 16;
    const u16* src = &Vh[((size_t)bh * S_ + st * 64 + r) * DK + c];
    *reinterpret_cast<u16x8*>(&T[r * 72 + c])     = *reinterpret_cast<const u16x8*>(src);
    *reinterpret_cast<u16x8*>(&T[r * 72 + c + 8]) = *reinterpret_cast<const u16x8*>(src + 8);
  }
  __syncthreads();
  {
    const int d = t >> 2, s0 = (t & 3) * 16;
    u16x8 a, b;
    #pragma unroll
    for (int i = 0; i < 8; ++i) a[i] = T[(s0 + i) * 72 + d];
    #pragma unroll
    for (int i = 0; i < 8; ++i) b[i] = T[(s0 + 8 + i) * 72 + d];
    u16* dst = &Vt[((size_t)bh * DK + d) * S_ + st * 64 + s0];
    *reinterpret_cast<u16x8*>(dst)     = a;
    *reinterpret_cast<u16x8*>(dst + 8) = b;
  }
}

// ---------------------------------------------------------------------------
// Flash causal attention, 32x32x16 MFMA (T12 structure), QBLK=128, KVBLK=64.
// 4 waves; wave w owns 32 q-rows. Per 64-key tile:
//   - K AND V in LDS (shared by all 4 waves), double-buffered via
//     global_load_lds, counted vmcnt(4), raw barriers (T3).
//   - S^T = K(A:32keys) x Q(B:32qrows) via 2 subtile x 4 k-step 32x32x16.
//     C col = qrow = lane&31 -> per-lane softmax (exp2, scale folded in Q).
//   - P handoff QK->PV ENTIRELY IN REGISTERS: cvt_pk pairs + permlane32_swap
//     (one swap fills two A-frag words). NO Ps LDS round-trip (was 32KB/unit
//     of the 112KB LDS-traffic ceiling measured in R1).
//   - Block decode: XCD-grouped (4 heads/XCD) + balanced pairing: co-resident
//     blocks (fid, fid+256) have qt summing to 15 -> per-CU work uniform 36
//     tile-iters (was 48 worst-case).
// ---------------------------------------------------------------------------
__global__ __launch_bounds__(256) void attn_kernel(
    const u16* __restrict__ Qh, const u16* __restrict__ Kh,
    const u16* __restrict__ Vt, float* __restrict__ out)
{
  __shared__ __align__(16) u16 Ks[2][64 * 64];   // [buf][key][dim]  (swizzled)
  __shared__ __align__(16) u16 Vs[2][64 * 64];   // [buf][dim][key]  (swizzled)
  __shared__ float Ls[4][32];                    // per-wave 1/l

  const int tid  = threadIdx.x;
  const int lane = tid & 63;
  const int w    = tid >> 6;
  const int l31  = lane & 31, hi = lane >> 5;
  const int x7   = l31 & 7;

  // decode: xcd = fid&7 (4 heads per XCD); qt pairing f(x)+f(x+8)=15, long first
  const int fid = blockIdx.x;
  const int bh  = (fid & 7) * 4 + ((fid >> 3) & 3);
  const int qtl = fid >> 5;
  const int qt  = (qtl < 8) ? (15 - 2 * qtl) : (2 * (qtl - 8));
  const int b   = bh >> 4, h = bh & 15;
  const int R0  = qt * 128;
  const int nt  = 2 * qt + 2;

  // Q as B-operand: B[k = s*16 + hi*8 + e][n = qrow = l31]
  bf16x8 qa[4];
  {
    const u16* qp = &Qh[((size_t)bh * S_ + R0 + w * 32 + l31) * DK + hi * 8];
    #pragma unroll
    for (int s = 0; s < 4; ++s)
      qa[s] = *reinterpret_cast<const bf16x8*>(qp + s * 16);
  }
  asm volatile("s_waitcnt vmcnt(0)" ::: "memory");   // clean vmcnt bookkeeping

  // staging (as R1): chunk c -> LDS (row=c>>3, unit c&7); src unit = (c&7)^(row&7)
  const u16* kb0 = Kh + (size_t)bh * S_ * DK;
  const u16* vb0 = Vt + (size_t)bh * DK * S_;
  const int r0 = tid >> 3, r1 = r0 + 32;
  const int cs = (tid & 7) ^ (r0 & 7);             // (r1&7)==(r0&7)
  const u16* sK0 = kb0 + r0 * DK + cs * 8;         // +4096/tile (64 key rows)
  const u16* sK1 = kb0 + r1 * DK + cs * 8;
  const u16* sV0 = vb0 + (size_t)r0 * S_ + cs * 8; // +64/tile (64 keys)
  const u16* sV1 = vb0 + (size_t)r1 * S_ + cs * 8;

  f32x16 oacc0 = {}, oacc1 = {};
  float lsum = 0.f;

  glds16(sK0, &Ks[0][tid * 8]);
  glds16(sK1, &Ks[0][2048 + tid * 8]);
  glds16(sV0, &Vs[0][tid * 8]);
  glds16(sV1, &Vs[0][2048 + tid * 8]);
  sK0 += 4096; sK1 += 4096; sV0 += 64; sV1 += 64;

  int cur = 0;
  for (int t = 0; t < nt; ++t) {
    if (t + 1 < nt) {
      glds16(sK0, &Ks[cur ^ 1][tid * 8]);
      glds16(sK1, &Ks[cur ^ 1][2048 + tid * 8]);
      glds16(sV0, &Vs[cur ^ 1][tid * 8]);
      glds16(sV1, &Vs[cur ^ 1][2048 + tid * 8]);
      sK0 += 4096; sK1 += 4096; sV0 += 64; sV1 += 64;
      asm volatile("s_waitcnt vmcnt(4)" ::: "memory");  // current tile landed
    } else {
      asm volatile("s_waitcnt vmcnt(0)" ::: "memory");
    }
    __builtin_amdgcn_s_barrier();
    asm volatile("" ::: "memory");

    const u16* Kb = Ks[cur];
    const u16* Vb = Vs[cur];

    // causal geometry (wave-uniform): base = wave rowbase - tile keybase
    const int base  = R0 + w * 32 - t * 64;
    const int ksmax = (base + 31) >> 5;              // subtile ks live iff ks<=ksmax
    const int ksm   = (ksmax > 1) ? 1 : ksmax;

    if (ksm >= 0) {
      // ---- QK^T: S^T[key][qrow], 2 key-subtiles x 4 k-steps of 32x32x16
      f32x16 sfr[2];
      __builtin_amdgcn_s_setprio(1);
      #pragma unroll
      for (int ks = 0; ks < 2; ++ks) {
        if (ks > ksm) break;
        const int rb = (ks * 32 + l31) * 64;
        f32x16 sf = {};
        #pragma unroll
        for (int s = 0; s < 4; ++s) {
          const bf16x8 af = *reinterpret_cast<const bf16x8*>(
              &Kb[rb + ((2 * s + hi) ^ x7) * 8]);
          sf = __builtin_amdgcn_mfma_f32_32x32x16_bf16(af, qa[s], sf, 0, 0, 0);
        }
        sfr[ks] = sf;
      }
      __builtin_amdgcn_s_setprio(0);

      // ---- softmax (per-lane: lane owns qrow l31's scores) + pack
      unsigned pku[2][4][2];                         // [ks][m][word]
      #pragma unroll
      for (int ks = 0; ks < 2; ++ks) {
        if (ks > ksm) break;
        const int Dg = base + l31 - 32 * ks - 4 * hi;   // per-lane causal bound
        const bool full = (base >= 32 * ks + 31);       // wave-uniform: no mask
        float e[16];
        #pragma unroll
        for (int r = 0; r < 16; ++r) {
          const int rk = (r & 3) + 8 * (r >> 2);        // kloc minus 4*hi
          const float ex = __builtin_amdgcn_exp2f(sfr[ks][r]);
          e[r] = (full || rk <= Dg) ? ex : 0.f;
        }
        float a01 = 0.f;
        #pragma unroll
        for (int r = 0; r < 16; ++r) a01 += e[r];
        lsum += a01;
        #pragma unroll
        for (int m = 0; m < 4; ++m) {
          pku[ks][m][0] = cvtpk(e[4 * m], e[4 * m + 1]);
          pku[ks][m][1] = cvtpk(e[4 * m + 2], e[4 * m + 3]);
        }
      }

      // ---- PV: O[qrow][dim] += P x V. A-frags built in-register via swaps.
      const int smax = 2 * ksm + 1;
      #pragma unroll
      for (int s = 0; s < 4; ++s) {
        if (s > smax) break;
        const int ks = s >> 1, p = s & 1;
        unsigned w0 = pku[ks][2 * p][0],     w1v = pku[ks][2 * p][1];
        unsigned w2 = pku[ks][2 * p + 1][0], w3  = pku[ks][2 * p + 1][1];
        plswap(w0, w2);                              // -> words 0,2
        plswap(w1v, w3);                             // -> words 1,3
        u32x4 paw; paw[0] = w0; paw[1] = w1v; paw[2] = w2; paw[3] = w3;
        const bf16x8 pa = *reinterpret_cast<const bf16x8*>(&paw);
        const int uv = ((2 * s + hi) ^ x7) * 8;
        const bf16x8 vb0f = *reinterpret_cast<const bf16x8*>(&Vb[l31 * 64 + uv]);
        const bf16x8 vb1f = *reinterpret_cast<const bf16x8*>(&Vb[(32 + l31) * 64 + uv]);
        __builtin_amdgcn_s_setprio(1);
        oacc0 = __builtin_amdgcn_mfma_f32_32x32x16_bf16(pa, vb0f, oacc0, 0, 0, 0);
        oacc1 = __builtin_amdgcn_mfma_f32_32x32x16_bf16(pa, vb1f, oacc1, 0, 0, 0);
        __builtin_amdgcn_s_setprio(0);
      }
    }

    asm volatile("" ::: "memory");
    __builtin_amdgcn_s_barrier();                    // bufs free for re-stage
    asm volatile("" ::: "memory");
    cur ^= 1;
  }

  // epilogue: qrow sums live per-lane (col side); oacc rows need them redistributed
  const float lt = lsum + __shfl_xor(lsum, 32, 64);
  if (hi == 0) Ls[w][l31] = 1.0f / lt;
  // oacc row r -> qrow-within-32 = (r&3)+8*(r>>2)+4*hi ; col = dim = ds*32+l31
  #pragma unroll
  for (int r = 0; r < 16; ++r) {
    const int rq = (r & 3) + 8 * (r >> 2) + 4 * hi;
    const float inv = Ls[w][rq];
    const int srow = R0 + w * 32 + rq;
    float* op = &out[(size_t)(b * S_ + srow) * DM + h * DK + l31];
    op[0]  = oacc0[r] * inv;
    op[32] = oacc1[r] * inv;
  }
}

extern "C" void kernel_launch(void* const* d_in, const int* in_sizes, int n_in,
                              void* d_out, int out_size, void* d_ws, size_t ws_size,
                              hipStream_t stream) {
  // inputs: q,k,v,mask,Wq,bq,Wk,bk,Wv,bv — fp32 (mask int32, unused)
  const float* q  = (const float*)d_in[0];
  const float* k  = (const float*)d_in[1];
  const float* v  = (const float*)d_in[2];
  const float* Wq = (const float*)d_in[4];
  const float* bq = (const float*)d_in[5];
  const float* Wk = (const float*)d_in[6];
  const float* bk = (const float*)d_in[7];
  const float* Wv = (const float*)d_in[8];
  const float* bv = (const float*)d_in[9];

  u16* Xq  = (u16*)d_ws;          // 8 MB each for X*, 2 MB each for W*
  u16* Xk  = Xq + NX;
  u16* Xv  = Xk + NX;
  u16* Wqb = Xv + NX;
  u16* Wkb = Wqb + NW;
  u16* Wvb = Wkb + NW;
  u16* Qh  = Wvb + NW;            // [bh][s][d]
  u16* Kh  = Qh + NX;             // [bh][s][d]
  u16* Vh  = Kh + NX;             // [bh][s][d]
  u16* Vt  = Xq;                  // [bh][d][s] — aliases Xq (dead after proj)

  cvt_kernel<<<dim3(NX / (256 * 8), 6), 256, 0, stream>>>(
      q, k, v, Wq, Wk, Wv, Xq, Xk, Xv, Wqb, Wkb, Wvb);
  proj_kernel<<<dim3(DM / 128, (B_ * S_) / 128, 3), 256, 0, stream>>>(
      Xq, Xk, Xv, Wqb, Wkb, Wvb, bq, bk, bv, Qh, Kh, Vh);
  transpose_kernel<<<dim3(S_ / 64, B_ * H_), 256, 0, stream>>>(Vh, Vt);
  attn_kernel<<<dim3(512), 256, 0, stream>>>(
      Qh, Kh, Vt, (float*)d_out);
}